// Round 5
// baseline (790.321 us; speedup 1.0000x reference)
//
#include <hip/hip_runtime.h>
#include <hip/hip_bf16.h>

// SO3TensorProductLayer: out = relu(128*(x (x) x) @ W1 + b1) @ W2 + b2
// h[c][b] = 128 * sum_i x[b,i] * (sum_j W1T[c][i*128+j] * x[b,j])
// gemm1: A = W1 packed in MFMA-fragment order (1KB contiguous wave loads,
// global->VGPR, depth-2 rotating buffer with end-guard, no K-loop barrier);
// B = x register-resident; per-i scalar fold by x[b,i] (fp32 xi via
// ds_read_b128, conflict-free). Partials bf16 in [z][b][c].
// __launch_bounds__(256,4) is load-bearing: forces acc into AGPRs and
// 4 blocks/CU (r4 dropped it -> VGPR 212, occupancy 11%, 124us).

typedef __attribute__((ext_vector_type(8))) short short8;   // 8 bf16
typedef __attribute__((ext_vector_type(4))) float floatx4;  // 4 fp32

__device__ __forceinline__ unsigned short f2bf(float f) {
    union { float f; unsigned int u; } v; v.f = f;
    unsigned int r = v.u + 0x7fffu + ((v.u >> 16) & 1u);   // RNE
    return (unsigned short)(r >> 16);
}
__device__ __forceinline__ float bf2f(unsigned short b) {
    union { unsigned int u; float f; } v; v.u = ((unsigned int)b) << 16;
    return v.f;
}

// ---------------------------------------------------------------------------
// Pack W1 [16384 K][512 C] fp32 -> W1Tp chunks of 1KB: chunk(c16,kc) holds
// A-fragment for c rows c16*16..+15, K cols kc*32..+31: wave load at
// (chunkBase + lane*16B) gives lane(m=lane&15,quad=lane>>4) the 8 bf16 of
// W1[K=kc*32+quad*8+j][c=c16*16+m].
__global__ __launch_bounds__(256) void pack_w1_kernel(
    const float* __restrict__ W1, unsigned short* __restrict__ W1Tp) {
    __shared__ float tile[64][65];
    const int k0 = blockIdx.x * 64;
    const int c0 = blockIdx.y * 64;
    const int tr = threadIdx.x >> 4;
    const int tc4 = (threadIdx.x & 15) * 4;
#pragma unroll
    for (int p = 0; p < 4; ++p) {
        int k = p * 16 + tr;
        float4 v = *(const float4*)(W1 + (long)(k0 + k) * 512 + c0 + tc4);
        tile[k][tc4 + 0] = v.x; tile[k][tc4 + 1] = v.y;
        tile[k][tc4 + 2] = v.z; tile[k][tc4 + 3] = v.w;
    }
    __syncthreads();
    const int lane = threadIdx.x & 63;
    const int w = threadIdx.x >> 6;
    const int m = lane & 15, quad = lane >> 4;
#pragma unroll
    for (int pass = 0; pass < 2; ++pass) {
        int chunk = w * 2 + pass;              // 0..7
        int kcL = chunk & 1, c16L = chunk >> 1;
        union { unsigned short s[8]; uint4 u; } o;
#pragma unroll
        for (int j = 0; j < 8; ++j)
            o.s[j] = f2bf(tile[kcL * 32 + quad * 8 + j][c16L * 16 + m]);
        long c16g = (c0 >> 4) + c16L;
        long kcg  = (k0 >> 5) + kcL;
        *(uint4*)(W1Tp + (c16g * 512 + kcg) * 512 + lane * 8) = o.u;
    }
}

// in: [R][C] fp32 -> out: [C][R] bf16 (for W2 -> W2T).
__global__ __launch_bounds__(256) void transpose_cast_kernel(
    const float* __restrict__ in, unsigned short* __restrict__ out, int R, int C) {
    __shared__ float tile[64][65];
    const int r0 = blockIdx.x * 64, c0 = blockIdx.y * 64;
    const int tr = threadIdx.x >> 4;
    const int tc4 = (threadIdx.x & 15) * 4;
#pragma unroll
    for (int p = 0; p < 4; ++p) {
        int r = p * 16 + tr;
        float4 v = *(const float4*)(in + (long)(r0 + r) * C + c0 + tc4);
        tile[r][tc4 + 0] = v.x; tile[r][tc4 + 1] = v.y;
        tile[r][tc4 + 2] = v.z; tile[r][tc4 + 3] = v.w;
    }
    __syncthreads();
#pragma unroll
    for (int p = 0; p < 4; ++p) {
        int c = p * 16 + tr;
        union { unsigned short s[4]; uint2 u; } pk;
#pragma unroll
        for (int e = 0; e < 4; ++e) pk.s[e] = f2bf(tile[tc4 + e][c]);
        *(uint2*)(out + (long)(c0 + c) * R + r0 + tc4) = pk.u;
    }
}

// ---------------------------------------------------------------------------
// gemm1: Pb[z][b][c] (bf16) over i-chunk z. 256 thr = 4 waves (2c x 2b),
// tile 64c x 128b. grid (32 b, 8 c, 4 z) -- b fastest (round-2 proven order).
__global__ __launch_bounds__(256, 4) void gemm1_kernel(
    const float* __restrict__ x,               // [4096][128]
    const unsigned short* __restrict__ W1Tp,
    unsigned short* __restrict__ Pb) {         // [4][4096][512] bf16
    __shared__ float xT[128][36];              // [b_local][i_local] fp32
    const int tid = threadIdx.x;
    const int b0 = blockIdx.x * 128;
    const int c0 = blockIdx.y * 64;
    const int zi = blockIdx.z;
    const int i0 = zi * 32;

    // stage xT[b][i] (fold multipliers), coalesced global reads
    for (int idx = tid; idx < 128 * 32; idx += 256) {
        int bL = idx >> 5, iL = idx & 31;
        xT[bL][iL] = x[(long)(b0 + bL) * 128 + i0 + iL];
    }
    __syncthreads();

    const int wid = tid >> 6;
    const int wm = wid >> 1, wn = wid & 1;
    const int lane = tid & 63;
    const int n16 = lane & 15, quad = lane >> 4;
    const int bBase = b0 + wn * 64;
    const int c16base = (c0 >> 4) + wm * 2;
    const int bLloc = wn * 64 + n16;           // xT row for tn=0

    floatx4 acc[2][4];
#pragma unroll
    for (int tm = 0; tm < 2; ++tm)
#pragma unroll
        for (int tn = 0; tn < 4; ++tn) acc[tm][tn] = (floatx4){0.f, 0.f, 0.f, 0.f};
    const floatx4 zero4 = (floatx4){0.f, 0.f, 0.f, 0.f};

#pragma unroll
    for (int jh = 0; jh < 2; ++jh) {
        // x B-fragments, register-resident for this j-half
        short8 Xf[2][4];
#pragma unroll
        for (int ks = 0; ks < 2; ++ks)
#pragma unroll
            for (int tn = 0; tn < 4; ++tn) {
                const float* xp = x + (long)(bBase + tn * 16 + n16) * 128
                                    + jh * 64 + ks * 32 + quad * 8;
                float4 v0 = *(const float4*)xp;
                float4 v1 = *(const float4*)(xp + 4);
                short8 f;
                f[0] = (short)f2bf(v0.x); f[1] = (short)f2bf(v0.y);
                f[2] = (short)f2bf(v0.z); f[3] = (short)f2bf(v0.w);
                f[4] = (short)f2bf(v1.x); f[5] = (short)f2bf(v1.y);
                f[6] = (short)f2bf(v1.z); f[7] = (short)f2bf(v1.w);
                Xf[ks][tn] = f;
            }
        // A chunk base pointers; per-i advance = 4 chunks = 2048 u16
        const unsigned short* aBase[2];
#pragma unroll
        for (int tm = 0; tm < 2; ++tm)
            aBase[tm] = W1Tp
                + ((long)(c16base + tm) * 512 + (long)i0 * 4 + jh * 2) * 512
                + lane * 8;

        short8 Abuf[2][2][2];                  // [stage][tm][ks] depth-2 ring
#pragma unroll
        for (int st = 0; st < 2; ++st)
#pragma unroll
            for (int tm = 0; tm < 2; ++tm)
#pragma unroll
                for (int ks = 0; ks < 2; ++ks)
                    Abuf[st][tm][ks] =
                        *(const short8*)(aBase[tm] + st * 2048 + ks * 512);

        float4 xi4[4];
#pragma unroll 4
        for (int i = 0; i < 32; ++i) {
            const int st = i & 1;
            if ((i & 3) == 0) {                // one ds_read_b128 per tn per 4 i
#pragma unroll
                for (int tn = 0; tn < 4; ++tn)
                    xi4[tn] = *(const float4*)&xT[bLloc + tn * 16][i];
            }
            float xi[4];
#pragma unroll
            for (int tn = 0; tn < 4; ++tn) {
                const float* fp = (const float*)&xi4[tn];
                xi[tn] = fp[i & 3];            // i&3 constant under unroll-4
            }
#pragma unroll
            for (int tm = 0; tm < 2; ++tm)
#pragma unroll
                for (int tn = 0; tn < 4; ++tn) {
                    floatx4 t = __builtin_amdgcn_mfma_f32_16x16x32_bf16(
                        Abuf[st][tm][0], Xf[0][tn], zero4, 0, 0, 0);
                    t = __builtin_amdgcn_mfma_f32_16x16x32_bf16(
                        Abuf[st][tm][1], Xf[1][tn], t, 0, 0, 0);
                    acc[tm][tn] += xi[tn] * t;
                }
            if (i < 30) {                      // guarded prefetch: no wrap reloads
#pragma unroll
                for (int tm = 0; tm < 2; ++tm)
#pragma unroll
                    for (int ks = 0; ks < 2; ++ks)
                        Abuf[st][tm][ks] = *(const short8*)(
                            aBase[tm] + (long)(i + 2) * 2048 + ks * 512);
            }
        }
    }

    // store bf16 partial in [z][b][c]: per (tm,tn) lane owns 4 c-consecutive
    unsigned short* pb = Pb + (long)zi * (4096L * 512);
#pragma unroll
    for (int tm = 0; tm < 2; ++tm)
#pragma unroll
        for (int tn = 0; tn < 4; ++tn) {
            int b = bBase + tn * 16 + n16;
            int cb = (c16base + tm) * 16 + quad * 4;
            union { unsigned short s[4]; uint2 u; } pk;
#pragma unroll
            for (int r = 0; r < 4; ++r) pk.s[r] = f2bf(acc[tm][tn][r]);
            *(uint2*)(pb + (long)b * 512 + cb) = pk.u;
        }
}

// ---------------------------------------------------------------------------
// tail: h[b][c] = relu(128*sum_z Pb[z][b][c] + b1[c]) (bf16, LDS), then
// out[b][o] = h @ W2T + b2. 256 thr = 4 waves; b-tile 16 (grid 256 blocks);
// each wave owns 64 o columns.
__global__ __launch_bounds__(256) void tail_kernel(
    const unsigned short* __restrict__ Pb,     // [4][4096][512] bf16
    const float* __restrict__ b1,              // [512]
    const unsigned short* __restrict__ W2T,    // [256][512] bf16
    const float* __restrict__ b2,              // [256]
    float* __restrict__ out) {                 // [4096][256]
    __shared__ unsigned short hL[16][516];
    __shared__ float b1s[512];
    const int tid = threadIdx.x;
    const int b0 = blockIdx.x * 16;
    b1s[tid] = b1[tid];
    b1s[tid + 256] = b1[tid + 256];
    __syncthreads();

    const unsigned int* Pu = (const unsigned int*)Pb;   // 2 bf16 per uint
#pragma unroll 4
    for (int idx = tid; idx < 16 * 256; idx += 256) {
        int bL = idx >> 8;                      // 0..15
        int cu = idx & 255;                     // uint index; c = 2*cu
        float s0 = 0.f, s1 = 0.f;
#pragma unroll
        for (int z = 0; z < 4; ++z) {
            unsigned int u = Pu[((long)z * 4096 + b0 + bL) * 256 + cu];
            s0 += bf2f((unsigned short)(u & 0xffff));
            s1 += bf2f((unsigned short)(u >> 16));
        }
        int c = cu * 2;
        float v0 = fmaxf(fmaf(128.f, s0, b1s[c]), 0.f);
        float v1 = fmaxf(fmaf(128.f, s1, b1s[c + 1]), 0.f);
        unsigned int pk = (unsigned int)f2bf(v0) | ((unsigned int)f2bf(v1) << 16);
        *(unsigned int*)&hL[bL][c] = pk;
    }
    __syncthreads();

    const int w = tid >> 6, lane = tid & 63;
    const int n16 = lane & 15, quad = lane >> 4;
    const int o0 = w * 64;
    floatx4 acc[4];
#pragma unroll
    for (int tn = 0; tn < 4; ++tn) acc[tn] = (floatx4){0.f, 0.f, 0.f, 0.f};

#pragma unroll 4
    for (int ks = 0; ks < 16; ++ks) {
        short8 Af, Bf[4];
        {
            const unsigned short* p = &hL[n16][ks * 32 + quad * 8];
            union { uint2 u[2]; short8 s; } cvt;
            cvt.u[0] = *(const uint2*)p;
            cvt.u[1] = *(const uint2*)(p + 4);
            Af = cvt.s;
        }
#pragma unroll
        for (int tn = 0; tn < 4; ++tn)
            Bf[tn] = *(const short8*)(W2T + (long)(o0 + tn * 16 + n16) * 512
                                      + ks * 32 + quad * 8);
#pragma unroll
        for (int tn = 0; tn < 4; ++tn)
            acc[tn] = __builtin_amdgcn_mfma_f32_16x16x32_bf16(
                Af, Bf[tn], acc[tn], 0, 0, 0);
    }
#pragma unroll
    for (int tn = 0; tn < 4; ++tn) {
        float bias = b2[o0 + tn * 16 + n16];
#pragma unroll
        for (int r = 0; r < 4; ++r)
            out[(long)(b0 + quad * 4 + r) * 256
                + o0 + tn * 16 + n16] = acc[tn][r] + bias;
    }
}

extern "C" void kernel_launch(void* const* d_in, const int* in_sizes, int n_in,
                              void* d_out, int out_size, void* d_ws, size_t ws_size,
                              hipStream_t stream) {
    const float* x  = (const float*)d_in[0];   // [4096,128]
    const float* W1 = (const float*)d_in[1];   // [16384,512]
    const float* b1 = (const float*)d_in[2];   // [512]
    const float* W2 = (const float*)d_in[3];   // [512,256]
    const float* b2 = (const float*)d_in[4];   // [256]
    float* out = (float*)d_out;                // [4096,256]

    char* ws = (char*)d_ws;
    unsigned short* W1Tp = (unsigned short*)(ws);                 // 16.78 MB
    unsigned short* W2T  = (unsigned short*)(ws + 16777216);      // 0.26 MB
    unsigned short* Pb   = (unsigned short*)(ws + 16777216 + 262144); // 16.78 MB bf16

    pack_w1_kernel<<<dim3(256, 8), 256, 0, stream>>>(W1, W1Tp);
    transpose_cast_kernel<<<dim3(8, 4), 256, 0, stream>>>(W2, W2T, 512, 256);
    gemm1_kernel<<<dim3(32, 8, 4), 256, 0, stream>>>(x, W1Tp, Pb);
    tail_kernel<<<dim3(256), 256, 0, stream>>>(Pb, b1, W2T, b2, out);
}

// Round 6
// 184.641 us; speedup vs baseline: 4.2803x; 4.2803x over previous
//
#include <hip/hip_runtime.h>
#include <hip/hip_bf16.h>

// SO3TensorProductLayer: out = relu(128*(x (x) x) @ W1 + b1) @ W2 + b2
// h[c][b] = 128 * sum_i x[b,i] * (sum_j W1T[c][i*128+j] * x[b,j])
// gemm1: A = W1 packed in MFMA-fragment order (1KB contiguous wave loads,
// global->VGPR, depth-2 wrap ring, no K-loop barrier); B = x register-
// resident; per-i fold xi via direct ds_read_b32 (fp32 xT, 2-way = free).
// REGALLOC NOTE (r4/r5 lesson): the 256,4 launch bound caps VGPR at 128.
// Body must naturally fit (r2's does, ~64); address-taken local arrays
// (float4 xi buffers) inflate demand -> scratch spill -> 2 GB HBM traffic.
// Partials bf16 [z][b][c] (r4-proven: halves write traffic, tail-friendly).

typedef __attribute__((ext_vector_type(8))) short short8;   // 8 bf16
typedef __attribute__((ext_vector_type(4))) float floatx4;  // 4 fp32

__device__ __forceinline__ unsigned short f2bf(float f) {
    union { float f; unsigned int u; } v; v.f = f;
    unsigned int r = v.u + 0x7fffu + ((v.u >> 16) & 1u);   // RNE
    return (unsigned short)(r >> 16);
}
__device__ __forceinline__ float bf2f(unsigned short b) {
    union { unsigned int u; float f; } v; v.u = ((unsigned int)b) << 16;
    return v.f;
}

// ---------------------------------------------------------------------------
// Pack W1 [16384 K][512 C] fp32 -> W1Tp chunks of 1KB: chunk(c16,kc) holds
// A-fragment for c rows c16*16..+15, K cols kc*32..+31: wave load at
// (chunkBase + lane*16B) gives lane(m=lane&15,quad=lane>>4) the 8 bf16 of
// W1[K=kc*32+quad*8+j][c=c16*16+m].
__global__ __launch_bounds__(256) void pack_w1_kernel(
    const float* __restrict__ W1, unsigned short* __restrict__ W1Tp) {
    __shared__ float tile[64][65];
    const int k0 = blockIdx.x * 64;
    const int c0 = blockIdx.y * 64;
    const int tr = threadIdx.x >> 4;
    const int tc4 = (threadIdx.x & 15) * 4;
#pragma unroll
    for (int p = 0; p < 4; ++p) {
        int k = p * 16 + tr;
        float4 v = *(const float4*)(W1 + (long)(k0 + k) * 512 + c0 + tc4);
        tile[k][tc4 + 0] = v.x; tile[k][tc4 + 1] = v.y;
        tile[k][tc4 + 2] = v.z; tile[k][tc4 + 3] = v.w;
    }
    __syncthreads();
    const int lane = threadIdx.x & 63;
    const int w = threadIdx.x >> 6;
    const int m = lane & 15, quad = lane >> 4;
#pragma unroll
    for (int pass = 0; pass < 2; ++pass) {
        int chunk = w * 2 + pass;              // 0..7
        int kcL = chunk & 1, c16L = chunk >> 1;
        union { unsigned short s[8]; uint4 u; } o;
#pragma unroll
        for (int j = 0; j < 8; ++j)
            o.s[j] = f2bf(tile[kcL * 32 + quad * 8 + j][c16L * 16 + m]);
        long c16g = (c0 >> 4) + c16L;
        long kcg  = (k0 >> 5) + kcL;
        *(uint4*)(W1Tp + (c16g * 512 + kcg) * 512 + lane * 8) = o.u;
    }
}

// in: [R][C] fp32 -> out: [C][R] bf16 (for W2 -> W2T).
__global__ __launch_bounds__(256) void transpose_cast_kernel(
    const float* __restrict__ in, unsigned short* __restrict__ out, int R, int C) {
    __shared__ float tile[64][65];
    const int r0 = blockIdx.x * 64, c0 = blockIdx.y * 64;
    const int tr = threadIdx.x >> 4;
    const int tc4 = (threadIdx.x & 15) * 4;
#pragma unroll
    for (int p = 0; p < 4; ++p) {
        int r = p * 16 + tr;
        float4 v = *(const float4*)(in + (long)(r0 + r) * C + c0 + tc4);
        tile[r][tc4 + 0] = v.x; tile[r][tc4 + 1] = v.y;
        tile[r][tc4 + 2] = v.z; tile[r][tc4 + 3] = v.w;
    }
    __syncthreads();
#pragma unroll
    for (int p = 0; p < 4; ++p) {
        int c = p * 16 + tr;
        union { unsigned short s[4]; uint2 u; } pk;
#pragma unroll
        for (int e = 0; e < 4; ++e) pk.s[e] = f2bf(tile[tc4 + e][c]);
        *(uint2*)(out + (long)(c0 + c) * R + r0 + tc4) = pk.u;
    }
}

// ---------------------------------------------------------------------------
// gemm1: Pb[z][b][c] (bf16) over i-chunk z. 256 thr = 4 waves (2c x 2b),
// tile 64c x 128b. grid (32 b, 8 c, 4 z) -- b fastest (r2-proven order).
__global__ __launch_bounds__(256, 4) void gemm1_kernel(
    const float* __restrict__ x,               // [4096][128]
    const unsigned short* __restrict__ W1Tp,
    unsigned short* __restrict__ Pb) {         // [4][4096][512] bf16
    __shared__ float xT[128][36];              // [b_local][i_local] fp32
    const int tid = threadIdx.x;
    const int b0 = blockIdx.x * 128;
    const int c0 = blockIdx.y * 64;
    const int zi = blockIdx.z;
    const int i0 = zi * 32;

    // stage xT[b][i] (fold multipliers), coalesced global reads, no cast
    for (int idx = tid; idx < 128 * 32; idx += 256) {
        int bL = idx >> 5, iL = idx & 31;
        xT[bL][iL] = x[(long)(b0 + bL) * 128 + i0 + iL];
    }
    __syncthreads();

    const int wid = tid >> 6;
    const int wm = wid >> 1, wn = wid & 1;
    const int lane = tid & 63;
    const int n16 = lane & 15, quad = lane >> 4;
    const int bBase = b0 + wn * 64;
    const int c16base = (c0 >> 4) + wm * 2;
    const int bLloc = wn * 64 + n16;           // xT row for tn=0

    floatx4 acc[2][4];
#pragma unroll
    for (int tm = 0; tm < 2; ++tm)
#pragma unroll
        for (int tn = 0; tn < 4; ++tn) acc[tm][tn] = (floatx4){0.f, 0.f, 0.f, 0.f};
    const floatx4 zero4 = (floatx4){0.f, 0.f, 0.f, 0.f};

#pragma unroll
    for (int jh = 0; jh < 2; ++jh) {
        // x B-fragments, register-resident for this j-half
        short8 Xf[2][4];
#pragma unroll
        for (int ks = 0; ks < 2; ++ks)
#pragma unroll
            for (int tn = 0; tn < 4; ++tn) {
                const float* xp = x + (long)(bBase + tn * 16 + n16) * 128
                                    + jh * 64 + ks * 32 + quad * 8;
                float4 v0 = *(const float4*)xp;
                float4 v1 = *(const float4*)(xp + 4);
                short8 f;
                f[0] = (short)f2bf(v0.x); f[1] = (short)f2bf(v0.y);
                f[2] = (short)f2bf(v0.z); f[3] = (short)f2bf(v0.w);
                f[4] = (short)f2bf(v1.x); f[5] = (short)f2bf(v1.y);
                f[6] = (short)f2bf(v1.z); f[7] = (short)f2bf(v1.w);
                Xf[ks][tn] = f;
            }
        // A chunk base pointers; per-i advance = 4 chunks = 2048 u16
        const unsigned short* aBase[2][2];
#pragma unroll
        for (int tm = 0; tm < 2; ++tm)
#pragma unroll
            for (int ks = 0; ks < 2; ++ks)
                aBase[tm][ks] = W1Tp
                    + ((long)(c16base + tm) * 512 + (long)i0 * 4 + jh * 2 + ks) * 512
                    + lane * 8;

        short8 Abuf[2][2][2];                  // [stage][tm][ks] depth-2 ring
#pragma unroll
        for (int tm = 0; tm < 2; ++tm)
#pragma unroll
            for (int ks = 0; ks < 2; ++ks) {
                Abuf[0][tm][ks] = *(const short8*)(aBase[tm][ks]);
                Abuf[1][tm][ks] = *(const short8*)(aBase[tm][ks] + 2048);
            }

#pragma unroll 4
        for (int i = 0; i < 32; ++i) {
            const int st = i & 1;
            float xi[4];                       // direct ds_read_b32, no buffer array
#pragma unroll
            for (int tn = 0; tn < 4; ++tn)
                xi[tn] = xT[bLloc + tn * 16][i];
#pragma unroll
            for (int tm = 0; tm < 2; ++tm)
#pragma unroll
                for (int tn = 0; tn < 4; ++tn) {
                    floatx4 t = __builtin_amdgcn_mfma_f32_16x16x32_bf16(
                        Abuf[st][tm][0], Xf[0][tn], zero4, 0, 0, 0);
                    t = __builtin_amdgcn_mfma_f32_16x16x32_bf16(
                        Abuf[st][tm][1], Xf[1][tn], t, 0, 0, 0);
                    acc[tm][tn] += xi[tn] * t;
                }
            const int pi = (i + 2) & 31;       // wrap: tail reload is harmless
#pragma unroll
            for (int tm = 0; tm < 2; ++tm)
#pragma unroll
                for (int ks = 0; ks < 2; ++ks)
                    Abuf[st][tm][ks] =
                        *(const short8*)(aBase[tm][ks] + (long)pi * 2048);
        }
    }

    // store bf16 partial in [z][b][c]: per (tm,tn) lane owns 4 c-consecutive
    unsigned short* pb = Pb + (long)zi * (4096L * 512);
#pragma unroll
    for (int tm = 0; tm < 2; ++tm)
#pragma unroll
        for (int tn = 0; tn < 4; ++tn) {
            int b = bBase + tn * 16 + n16;
            int cb = (c16base + tm) * 16 + quad * 4;
            union { unsigned short s[4]; uint2 u; } pk;
#pragma unroll
            for (int r = 0; r < 4; ++r) pk.s[r] = f2bf(acc[tm][tn][r]);
            *(uint2*)(pb + (long)b * 512 + cb) = pk.u;
        }
}

// ---------------------------------------------------------------------------
// tail: h[b][c] = relu(128*sum_z Pb[z][b][c] + b1[c]) (bf16, LDS), then
// out[b][o] = h @ W2T + b2. 256 thr = 4 waves; b-tile 16 (grid 256 blocks);
// each wave owns 64 o columns.
__global__ __launch_bounds__(256) void tail_kernel(
    const unsigned short* __restrict__ Pb,     // [4][4096][512] bf16
    const float* __restrict__ b1,              // [512]
    const unsigned short* __restrict__ W2T,    // [256][512] bf16
    const float* __restrict__ b2,              // [256]
    float* __restrict__ out) {                 // [4096][256]
    __shared__ unsigned short hL[16][516];
    __shared__ float b1s[512];
    const int tid = threadIdx.x;
    const int b0 = blockIdx.x * 16;
    b1s[tid] = b1[tid];
    b1s[tid + 256] = b1[tid + 256];
    __syncthreads();

    const unsigned int* Pu = (const unsigned int*)Pb;   // 2 bf16 per uint
#pragma unroll 4
    for (int idx = tid; idx < 16 * 256; idx += 256) {
        int bL = idx >> 8;                      // 0..15
        int cu = idx & 255;                     // uint index; c = 2*cu
        float s0 = 0.f, s1 = 0.f;
#pragma unroll
        for (int z = 0; z < 4; ++z) {
            unsigned int u = Pu[((long)z * 4096 + b0 + bL) * 256 + cu];
            s0 += bf2f((unsigned short)(u & 0xffff));
            s1 += bf2f((unsigned short)(u >> 16));
        }
        int c = cu * 2;
        float v0 = fmaxf(fmaf(128.f, s0, b1s[c]), 0.f);
        float v1 = fmaxf(fmaf(128.f, s1, b1s[c + 1]), 0.f);
        unsigned int pk = (unsigned int)f2bf(v0) | ((unsigned int)f2bf(v1) << 16);
        *(unsigned int*)&hL[bL][c] = pk;
    }
    __syncthreads();

    const int w = tid >> 6, lane = tid & 63;
    const int n16 = lane & 15, quad = lane >> 4;
    const int o0 = w * 64;
    floatx4 acc[4];
#pragma unroll
    for (int tn = 0; tn < 4; ++tn) acc[tn] = (floatx4){0.f, 0.f, 0.f, 0.f};

#pragma unroll 4
    for (int ks = 0; ks < 16; ++ks) {
        short8 Af, Bf[4];
        {
            const unsigned short* p = &hL[n16][ks * 32 + quad * 8];
            union { uint2 u[2]; short8 s; } cvt;
            cvt.u[0] = *(const uint2*)p;
            cvt.u[1] = *(const uint2*)(p + 4);
            Af = cvt.s;
        }
#pragma unroll
        for (int tn = 0; tn < 4; ++tn)
            Bf[tn] = *(const short8*)(W2T + (long)(o0 + tn * 16 + n16) * 512
                                      + ks * 32 + quad * 8);
#pragma unroll
        for (int tn = 0; tn < 4; ++tn)
            acc[tn] = __builtin_amdgcn_mfma_f32_16x16x32_bf16(
                Af, Bf[tn], acc[tn], 0, 0, 0);
    }
#pragma unroll
    for (int tn = 0; tn < 4; ++tn) {
        float bias = b2[o0 + tn * 16 + n16];
#pragma unroll
        for (int r = 0; r < 4; ++r)
            out[(long)(b0 + quad * 4 + r) * 256
                + o0 + tn * 16 + n16] = acc[tn][r] + bias;
    }
}

extern "C" void kernel_launch(void* const* d_in, const int* in_sizes, int n_in,
                              void* d_out, int out_size, void* d_ws, size_t ws_size,
                              hipStream_t stream) {
    const float* x  = (const float*)d_in[0];   // [4096,128]
    const float* W1 = (const float*)d_in[1];   // [16384,512]
    const float* b1 = (const float*)d_in[2];   // [512]
    const float* W2 = (const float*)d_in[3];   // [512,256]
    const float* b2 = (const float*)d_in[4];   // [256]
    float* out = (float*)d_out;                // [4096,256]

    char* ws = (char*)d_ws;
    unsigned short* W1Tp = (unsigned short*)(ws);                 // 16.78 MB
    unsigned short* W2T  = (unsigned short*)(ws + 16777216);      // 0.26 MB
    unsigned short* Pb   = (unsigned short*)(ws + 16777216 + 262144); // 16.78 MB bf16

    pack_w1_kernel<<<dim3(256, 8), 256, 0, stream>>>(W1, W1Tp);
    transpose_cast_kernel<<<dim3(8, 4), 256, 0, stream>>>(W2, W2T, 512, 256);
    gemm1_kernel<<<dim3(32, 8, 4), 256, 0, stream>>>(x, W1Tp, Pb);
    tail_kernel<<<dim3(256), 256, 0, stream>>>(Pb, b1, W2T, b2, out);
}

// Round 7
// 177.119 us; speedup vs baseline: 4.4621x; 1.0425x over previous
//
#include <hip/hip_runtime.h>
#include <hip/hip_bf16.h>

// SO3TensorProductLayer: out = relu(128*(x (x) x) @ W1 + b1) @ W2 + b2
// h[c][b] = 128 * sum_i x[b,i] * (sum_j W1T[c][i*128+j] * x[b,j])
// gemm1 v3: A = W1 packed in MFMA-fragment order, global->VGPR depth-2 ring,
// no K-loop barrier. Wave tile c32 x b128 (tn=8): each 1KB A-chunk now feeds
// 8 MFMAs -> 128 FLOP/A-byte, halving L2->CU demand vs r6 (which profiled
// L2-BW-bound at MfmaUtil 31%). 2 blocks/CU, 2 waves/SIMD, cap 256 VGPR.
// REGALLOC (r5 lesson): no address-taken local arrays; xi scalars only.
// Partials bf16 [z][b][c] (r4-proven).

typedef __attribute__((ext_vector_type(8))) short short8;   // 8 bf16
typedef __attribute__((ext_vector_type(4))) float floatx4;  // 4 fp32

__device__ __forceinline__ unsigned short f2bf(float f) {
    union { float f; unsigned int u; } v; v.f = f;
    unsigned int r = v.u + 0x7fffu + ((v.u >> 16) & 1u);   // RNE
    return (unsigned short)(r >> 16);
}
__device__ __forceinline__ float bf2f(unsigned short b) {
    union { unsigned int u; float f; } v; v.u = ((unsigned int)b) << 16;
    return v.f;
}

// ---------------------------------------------------------------------------
// Pack W1 [16384 K][512 C] fp32 -> W1Tp chunks of 1KB: chunk(c16,kc) holds
// A-fragment for c rows c16*16..+15, K cols kc*32..+31: wave load at
// (chunkBase + lane*16B) gives lane(m=lane&15,quad=lane>>4) the 8 bf16 of
// W1[K=kc*32+quad*8+j][c=c16*16+m].
__global__ __launch_bounds__(256) void pack_w1_kernel(
    const float* __restrict__ W1, unsigned short* __restrict__ W1Tp) {
    __shared__ float tile[64][65];
    const int k0 = blockIdx.x * 64;
    const int c0 = blockIdx.y * 64;
    const int tr = threadIdx.x >> 4;
    const int tc4 = (threadIdx.x & 15) * 4;
#pragma unroll
    for (int p = 0; p < 4; ++p) {
        int k = p * 16 + tr;
        float4 v = *(const float4*)(W1 + (long)(k0 + k) * 512 + c0 + tc4);
        tile[k][tc4 + 0] = v.x; tile[k][tc4 + 1] = v.y;
        tile[k][tc4 + 2] = v.z; tile[k][tc4 + 3] = v.w;
    }
    __syncthreads();
    const int lane = threadIdx.x & 63;
    const int w = threadIdx.x >> 6;
    const int m = lane & 15, quad = lane >> 4;
#pragma unroll
    for (int pass = 0; pass < 2; ++pass) {
        int chunk = w * 2 + pass;              // 0..7
        int kcL = chunk & 1, c16L = chunk >> 1;
        union { unsigned short s[8]; uint4 u; } o;
#pragma unroll
        for (int j = 0; j < 8; ++j)
            o.s[j] = f2bf(tile[kcL * 32 + quad * 8 + j][c16L * 16 + m]);
        long c16g = (c0 >> 4) + c16L;
        long kcg  = (k0 >> 5) + kcL;
        *(uint4*)(W1Tp + (c16g * 512 + kcg) * 512 + lane * 8) = o.u;
    }
}

// in: [R][C] fp32 -> out: [C][R] bf16 (for W2 -> W2T).
__global__ __launch_bounds__(256) void transpose_cast_kernel(
    const float* __restrict__ in, unsigned short* __restrict__ out, int R, int C) {
    __shared__ float tile[64][65];
    const int r0 = blockIdx.x * 64, c0 = blockIdx.y * 64;
    const int tr = threadIdx.x >> 4;
    const int tc4 = (threadIdx.x & 15) * 4;
#pragma unroll
    for (int p = 0; p < 4; ++p) {
        int r = p * 16 + tr;
        float4 v = *(const float4*)(in + (long)(r0 + r) * C + c0 + tc4);
        tile[r][tc4 + 0] = v.x; tile[r][tc4 + 1] = v.y;
        tile[r][tc4 + 2] = v.z; tile[r][tc4 + 3] = v.w;
    }
    __syncthreads();
#pragma unroll
    for (int p = 0; p < 4; ++p) {
        int c = p * 16 + tr;
        union { unsigned short s[4]; uint2 u; } pk;
#pragma unroll
        for (int e = 0; e < 4; ++e) pk.s[e] = f2bf(tile[tc4 + e][c]);
        *(uint2*)(out + (long)(c0 + c) * R + r0 + tc4) = pk.u;
    }
}

// ---------------------------------------------------------------------------
// gemm1 v3: Pb[z][b][c] (bf16) over i-chunk z. 256 thr = 4 waves (2wm c x
// 2wn b); wave tile c32 x b128 (tm=2, tn=8); block tile c64 x b256.
// grid (16 b, 8 c, 4 z) = 512 blocks, b fastest.
__global__ __launch_bounds__(256, 2) void gemm1_kernel(
    const float* __restrict__ x,               // [4096][128]
    const unsigned short* __restrict__ W1Tp,
    unsigned short* __restrict__ Pb) {         // [4][4096][512] bf16
    __shared__ float xT[256][34];              // [b_local][i_local]; stride 34 -> conflict-free
    const int tid = threadIdx.x;
    const int b0 = blockIdx.x * 256;
    const int c0 = blockIdx.y * 64;
    const int zi = blockIdx.z;
    const int i0 = zi * 32;

    // stage xT[b][i] (fold multipliers), coalesced global reads
    for (int idx = tid; idx < 256 * 32; idx += 256) {
        int bL = idx >> 5, iL = idx & 31;
        xT[bL][iL] = x[(long)(b0 + bL) * 128 + i0 + iL];
    }
    __syncthreads();

    const int wid = tid >> 6;
    const int wm = wid >> 1, wn = wid & 1;
    const int lane = tid & 63;
    const int n16 = lane & 15, quad = lane >> 4;
    const int bBase = b0 + wn * 128;
    const int c16base = (c0 >> 4) + wm * 2;
    const int bLloc = wn * 128 + n16;          // xT row for tn=0

    floatx4 acc[2][8];
#pragma unroll
    for (int tm = 0; tm < 2; ++tm)
#pragma unroll
        for (int tn = 0; tn < 8; ++tn) acc[tm][tn] = (floatx4){0.f, 0.f, 0.f, 0.f};
    const floatx4 zero4 = (floatx4){0.f, 0.f, 0.f, 0.f};

#pragma unroll
    for (int jh = 0; jh < 2; ++jh) {
        // x B-fragments, register-resident for this j-half (64 VGPRs)
        short8 Xf[2][8];
#pragma unroll
        for (int ks = 0; ks < 2; ++ks)
#pragma unroll
            for (int tn = 0; tn < 8; ++tn) {
                const float* xp = x + (long)(bBase + tn * 16 + n16) * 128
                                    + jh * 64 + ks * 32 + quad * 8;
                float4 v0 = *(const float4*)xp;
                float4 v1 = *(const float4*)(xp + 4);
                short8 f;
                f[0] = (short)f2bf(v0.x); f[1] = (short)f2bf(v0.y);
                f[2] = (short)f2bf(v0.z); f[3] = (short)f2bf(v0.w);
                f[4] = (short)f2bf(v1.x); f[5] = (short)f2bf(v1.y);
                f[6] = (short)f2bf(v1.z); f[7] = (short)f2bf(v1.w);
                Xf[ks][tn] = f;
            }
        // A chunk base pointers; per-i advance = 4 chunks = 2048 u16
        const unsigned short* aBase[2][2];
#pragma unroll
        for (int tm = 0; tm < 2; ++tm)
#pragma unroll
            for (int ks = 0; ks < 2; ++ks)
                aBase[tm][ks] = W1Tp
                    + ((long)(c16base + tm) * 512 + (long)i0 * 4 + jh * 2 + ks) * 512
                    + lane * 8;

        short8 Abuf[2][2][2];                  // [stage][tm][ks] depth-2 ring
#pragma unroll
        for (int tm = 0; tm < 2; ++tm)
#pragma unroll
            for (int ks = 0; ks < 2; ++ks) {
                Abuf[0][tm][ks] = *(const short8*)(aBase[tm][ks]);
                Abuf[1][tm][ks] = *(const short8*)(aBase[tm][ks] + 2048);
            }

#pragma unroll 2
        for (int i = 0; i < 32; ++i) {
            const int st = i & 1;
            float xi[8];                       // scalarized under unroll (no addr-taken)
#pragma unroll
            for (int tn = 0; tn < 8; ++tn)
                xi[tn] = xT[bLloc + tn * 16][i];
#pragma unroll
            for (int tm = 0; tm < 2; ++tm)
#pragma unroll
                for (int tn = 0; tn < 8; ++tn) {
                    floatx4 t = __builtin_amdgcn_mfma_f32_16x16x32_bf16(
                        Abuf[st][tm][0], Xf[0][tn], zero4, 0, 0, 0);
                    t = __builtin_amdgcn_mfma_f32_16x16x32_bf16(
                        Abuf[st][tm][1], Xf[1][tn], t, 0, 0, 0);
                    acc[tm][tn] += xi[tn] * t;
                }
            const int pi = (i + 2) & 31;       // wrap: tail reload is harmless
#pragma unroll
            for (int tm = 0; tm < 2; ++tm)
#pragma unroll
                for (int ks = 0; ks < 2; ++ks)
                    Abuf[st][tm][ks] =
                        *(const short8*)(aBase[tm][ks] + (long)pi * 2048);
        }
    }

    // store bf16 partial in [z][b][c]: per (tm,tn) lane owns 4 c-consecutive
    unsigned short* pb = Pb + (long)zi * (4096L * 512);
#pragma unroll
    for (int tm = 0; tm < 2; ++tm)
#pragma unroll
        for (int tn = 0; tn < 8; ++tn) {
            int b = bBase + tn * 16 + n16;
            int cb = (c16base + tm) * 16 + quad * 4;
            union { unsigned short s[4]; uint2 u; } pk;
#pragma unroll
            for (int r = 0; r < 4; ++r) pk.s[r] = f2bf(acc[tm][tn][r]);
            *(uint2*)(pb + (long)b * 512 + cb) = pk.u;
        }
}

// ---------------------------------------------------------------------------
// tail: h[b][c] = relu(128*sum_z Pb[z][b][c] + b1[c]) (bf16, LDS), then
// out[b][o] = h @ W2T + b2. 256 thr = 4 waves; b-tile 16 (grid 256 blocks);
// each wave owns 64 o columns.
__global__ __launch_bounds__(256) void tail_kernel(
    const unsigned short* __restrict__ Pb,     // [4][4096][512] bf16
    const float* __restrict__ b1,              // [512]
    const unsigned short* __restrict__ W2T,    // [256][512] bf16
    const float* __restrict__ b2,              // [256]
    float* __restrict__ out) {                 // [4096][256]
    __shared__ unsigned short hL[16][516];
    __shared__ float b1s[512];
    const int tid = threadIdx.x;
    const int b0 = blockIdx.x * 16;
    b1s[tid] = b1[tid];
    b1s[tid + 256] = b1[tid + 256];
    __syncthreads();

    const unsigned int* Pu = (const unsigned int*)Pb;   // 2 bf16 per uint
#pragma unroll 4
    for (int idx = tid; idx < 16 * 256; idx += 256) {
        int bL = idx >> 8;                      // 0..15
        int cu = idx & 255;                     // uint index; c = 2*cu
        float s0 = 0.f, s1 = 0.f;
#pragma unroll
        for (int z = 0; z < 4; ++z) {
            unsigned int u = Pu[((long)z * 4096 + b0 + bL) * 256 + cu];
            s0 += bf2f((unsigned short)(u & 0xffff));
            s1 += bf2f((unsigned short)(u >> 16));
        }
        int c = cu * 2;
        float v0 = fmaxf(fmaf(128.f, s0, b1s[c]), 0.f);
        float v1 = fmaxf(fmaf(128.f, s1, b1s[c + 1]), 0.f);
        unsigned int pk = (unsigned int)f2bf(v0) | ((unsigned int)f2bf(v1) << 16);
        *(unsigned int*)&hL[bL][c] = pk;
    }
    __syncthreads();

    const int w = tid >> 6, lane = tid & 63;
    const int n16 = lane & 15, quad = lane >> 4;
    const int o0 = w * 64;
    floatx4 acc[4];
#pragma unroll
    for (int tn = 0; tn < 4; ++tn) acc[tn] = (floatx4){0.f, 0.f, 0.f, 0.f};

#pragma unroll 4
    for (int ks = 0; ks < 16; ++ks) {
        short8 Af, Bf[4];
        {
            const unsigned short* p = &hL[n16][ks * 32 + quad * 8];
            union { uint2 u[2]; short8 s; } cvt;
            cvt.u[0] = *(const uint2*)p;
            cvt.u[1] = *(const uint2*)(p + 4);
            Af = cvt.s;
        }
#pragma unroll
        for (int tn = 0; tn < 4; ++tn)
            Bf[tn] = *(const short8*)(W2T + (long)(o0 + tn * 16 + n16) * 512
                                      + ks * 32 + quad * 8);
#pragma unroll
        for (int tn = 0; tn < 4; ++tn)
            acc[tn] = __builtin_amdgcn_mfma_f32_16x16x32_bf16(
                Af, Bf[tn], acc[tn], 0, 0, 0);
    }
#pragma unroll
    for (int tn = 0; tn < 4; ++tn) {
        float bias = b2[o0 + tn * 16 + n16];
#pragma unroll
        for (int r = 0; r < 4; ++r)
            out[(long)(b0 + quad * 4 + r) * 256
                + o0 + tn * 16 + n16] = acc[tn][r] + bias;
    }
}

extern "C" void kernel_launch(void* const* d_in, const int* in_sizes, int n_in,
                              void* d_out, int out_size, void* d_ws, size_t ws_size,
                              hipStream_t stream) {
    const float* x  = (const float*)d_in[0];   // [4096,128]
    const float* W1 = (const float*)d_in[1];   // [16384,512]
    const float* b1 = (const float*)d_in[2];   // [512]
    const float* W2 = (const float*)d_in[3];   // [512,256]
    const float* b2 = (const float*)d_in[4];   // [256]
    float* out = (float*)d_out;                // [4096,256]

    char* ws = (char*)d_ws;
    unsigned short* W1Tp = (unsigned short*)(ws);                 // 16.78 MB
    unsigned short* W2T  = (unsigned short*)(ws + 16777216);      // 0.26 MB
    unsigned short* Pb   = (unsigned short*)(ws + 16777216 + 262144); // 16.78 MB bf16

    pack_w1_kernel<<<dim3(256, 8), 256, 0, stream>>>(W1, W1Tp);
    transpose_cast_kernel<<<dim3(8, 4), 256, 0, stream>>>(W2, W2T, 512, 256);
    gemm1_kernel<<<dim3(16, 8, 4), 256, 0, stream>>>(x, W1Tp, Pb);
    tail_kernel<<<dim3(256), 256, 0, stream>>>(Pb, b1, W2T, b2, out);
}